// Round 5
// baseline (364.065 us; speedup 1.0000x reference)
//
#include <hip/hip_runtime.h>

// Per-voxel LUT gather + scale + onehot, all float32.
//   out[i]      = paren[i] * scale(lab[i]), scale(0) == 1.0  (bg bit-exact)
//   onehot ch0 = lab==0, ch1 = dark vessel, ch2 = bright vessel
// Traffic: 8 B read + 16 B write per voxel -> 403 MB -> ~64 us @ 6.3 TB/s.
// R5: single-variable test vs R4 — stores back to plain (temporal); loads
// stay non-temporal. 8 voxels/thread.

constexpr unsigned int VOX = 256u * 256u * 256u;  // 16,777,216
constexpr int N_IDS = 256;

typedef int   vint4  __attribute__((ext_vector_type(4)));
typedef float vflt4  __attribute__((ext_vector_type(4)));

__global__ __launch_bounds__(256)
void synth_semantic_kernel(const int* __restrict__ labels,
                           const float* __restrict__ id_intensity,
                           const int* __restrict__ id_is_dark,
                           const float* __restrict__ paren,
                           float* __restrict__ out)
{
    // LUT: bits[30:0] = f32 scale (id 0 forced to 1.0; scale in (0,2) so the
    // sign bit is free), bit 31 = dark flag. One ds_read_b32 per voxel.
    __shared__ unsigned int lut[N_IDS];
    const int t = threadIdx.x;
    {
        float sc = (t == 0) ? 1.0f : id_intensity[t];
        union { float f; unsigned int u; } cv; cv.f = sc;
        lut[t] = (cv.u & 0x7FFFFFFFu) | ((id_is_dark[t] == 1) ? 0x80000000u : 0u);
    }
    __syncthreads();

    const unsigned int tid  = blockIdx.x * 256u + (unsigned int)t;
    const unsigned int base = tid * 8u;  // 8 voxels/thread, exact coverage

    const vint4* lp = (const vint4*)(labels + base);
    const vint4 l0 = __builtin_nontemporal_load(lp);
    const vint4 l1 = __builtin_nontemporal_load(lp + 1);
    const vflt4* pp = (const vflt4*)(paren + base);
    const vflt4 p0 = __builtin_nontemporal_load(pp);
    const vflt4 p1 = __builtin_nontemporal_load(pp + 1);

    const int   labs[8] = {l0.x, l0.y, l0.z, l0.w, l1.x, l1.y, l1.z, l1.w};
    const float pv[8]   = {p0.x, p0.y, p0.z, p0.w, p1.x, p1.y, p1.z, p1.w};

    float o[8], bg[8], dk[8], br[8];
#pragma unroll
    for (int j = 0; j < 8; ++j) {
        const int lab = labs[j];
        const unsigned int e = lut[lab];
        union { unsigned int u; float f; } sc; sc.u = e & 0x7FFFFFFFu;
        const bool isbg = (lab == 0);
        const bool isdk = (!isbg) && (e >> 31);
        const bool isbr = (!isbg) && !(e >> 31);
        o[j]  = pv[j] * sc.f;          // bg: *1.0f, bit-exact
        bg[j] = isbg ? 1.0f : 0.0f;
        dk[j] = isdk ? 1.0f : 0.0f;
        br[j] = isbr ? 1.0f : 0.0f;
    }

    vflt4* po  = (vflt4*)(out + base);
    vflt4* pbg = (vflt4*)(out + VOX + base);
    vflt4* pdk = (vflt4*)(out + 2u * VOX + base);
    vflt4* pbr = (vflt4*)(out + 3u * VOX + base);
    po[0]  = (vflt4){o[0],  o[1],  o[2],  o[3]};
    po[1]  = (vflt4){o[4],  o[5],  o[6],  o[7]};
    pbg[0] = (vflt4){bg[0], bg[1], bg[2], bg[3]};
    pbg[1] = (vflt4){bg[4], bg[5], bg[6], bg[7]};
    pdk[0] = (vflt4){dk[0], dk[1], dk[2], dk[3]};
    pdk[1] = (vflt4){dk[4], dk[5], dk[6], dk[7]};
    pbr[0] = (vflt4){br[0], br[1], br[2], br[3]};
    pbr[1] = (vflt4){br[4], br[5], br[6], br[7]};
}

extern "C" void kernel_launch(void* const* d_in, const int* in_sizes, int n_in,
                              void* d_out, int out_size, void* d_ws, size_t ws_size,
                              hipStream_t stream) {
    const int*   labels  = (const int*)d_in[0];
    const float* id_int  = (const float*)d_in[1];
    const int*   id_dark = (const int*)d_in[2];
    const float* paren   = (const float*)d_in[3];
    float*       out     = (float*)d_out;

    const unsigned int threads_total = VOX / 8u;       // 2,097,152
    const unsigned int blocks = threads_total / 256u;  // 8,192
    synth_semantic_kernel<<<dim3(blocks), dim3(256), 0, stream>>>(
        labels, id_int, id_dark, paren, out);
}

// Round 6
// 355.735 us; speedup vs baseline: 1.0234x; 1.0234x over previous
//
#include <hip/hip_runtime.h>

// Per-voxel LUT gather + scale + onehot, all float32.
//   out[i]      = paren[i] * scale(lab[i]), scale(0) == 1.0  (bg bit-exact)
//   onehot ch0 = lab==0, ch1 = dark vessel, ch2 = bright vessel
// Traffic: 8 B read + 16 B write per voxel -> 403 MB -> ~64 us @ 6.3 TB/s.
// R6: wave-contiguous instruction footprints. Each thread handles two float4
// groups offset by 256 voxels (= one wave's float4 span), so every ld/st
// instruction covers a contiguous aligned 1 KB per wave (full cachelines),
// instead of the 32B-strided half-line footprint of the float4[2]/thread
// layout. NT loads + NT stores (R4 config otherwise).

constexpr unsigned int VOX = 256u * 256u * 256u;  // 16,777,216
constexpr int N_IDS = 256;

typedef int   vint4  __attribute__((ext_vector_type(4)));
typedef float vflt4  __attribute__((ext_vector_type(4)));

__global__ __launch_bounds__(256)
void synth_semantic_kernel(const int* __restrict__ labels,
                           const float* __restrict__ id_intensity,
                           const int* __restrict__ id_is_dark,
                           const float* __restrict__ paren,
                           float* __restrict__ out)
{
    // LUT: bits[30:0] = f32 scale (id 0 forced to 1.0; scale in (0,2) so the
    // sign bit is free), bit 31 = dark flag. One ds_read_b32 per voxel.
    __shared__ unsigned int lut[N_IDS];
    const int t = threadIdx.x;
    {
        float sc = (t == 0) ? 1.0f : id_intensity[t];
        union { float f; unsigned int u; } cv; cv.f = sc;
        lut[t] = (cv.u & 0x7FFFFFFFu) | ((id_is_dark[t] == 1) ? 0x80000000u : 0u);
    }
    __syncthreads();

    // Wave-contiguous addressing: wave w of the grid owns voxels
    // [gw*512, gw*512+512); lane l handles [gw*512 + 4l, +4) and
    // [gw*512 + 256 + 4l, +4). Each instruction -> contiguous 1 KB / wave.
    const unsigned int lane   = (unsigned int)t & 63u;
    const unsigned int wave   = (blockIdx.x * 256u + (unsigned int)t) >> 6;
    const unsigned int base0  = wave * 512u + lane * 4u;
    const unsigned int base1  = base0 + 256u;

    const vint4 l0 = __builtin_nontemporal_load((const vint4*)(labels + base0));
    const vint4 l1 = __builtin_nontemporal_load((const vint4*)(labels + base1));
    const vflt4 p0 = __builtin_nontemporal_load((const vflt4*)(paren + base0));
    const vflt4 p1 = __builtin_nontemporal_load((const vflt4*)(paren + base1));

    const int   labs[8] = {l0.x, l0.y, l0.z, l0.w, l1.x, l1.y, l1.z, l1.w};
    const float pv[8]   = {p0.x, p0.y, p0.z, p0.w, p1.x, p1.y, p1.z, p1.w};

    float o[8], bg[8], dk[8], br[8];
#pragma unroll
    for (int j = 0; j < 8; ++j) {
        const int lab = labs[j];
        const unsigned int e = lut[lab];
        union { unsigned int u; float f; } sc; sc.u = e & 0x7FFFFFFFu;
        const bool isbg = (lab == 0);
        const bool isdk = (!isbg) && (e >> 31);
        const bool isbr = (!isbg) && !(e >> 31);
        o[j]  = pv[j] * sc.f;          // bg: *1.0f, bit-exact
        bg[j] = isbg ? 1.0f : 0.0f;
        dk[j] = isdk ? 1.0f : 0.0f;
        br[j] = isbr ? 1.0f : 0.0f;
    }

    vflt4 v;
    v = (vflt4){o[0],  o[1],  o[2],  o[3]};
    __builtin_nontemporal_store(v, (vflt4*)(out + base0));
    v = (vflt4){o[4],  o[5],  o[6],  o[7]};
    __builtin_nontemporal_store(v, (vflt4*)(out + base1));
    v = (vflt4){bg[0], bg[1], bg[2], bg[3]};
    __builtin_nontemporal_store(v, (vflt4*)(out + VOX + base0));
    v = (vflt4){bg[4], bg[5], bg[6], bg[7]};
    __builtin_nontemporal_store(v, (vflt4*)(out + VOX + base1));
    v = (vflt4){dk[0], dk[1], dk[2], dk[3]};
    __builtin_nontemporal_store(v, (vflt4*)(out + 2u*VOX + base0));
    v = (vflt4){dk[4], dk[5], dk[6], dk[7]};
    __builtin_nontemporal_store(v, (vflt4*)(out + 2u*VOX + base1));
    v = (vflt4){br[0], br[1], br[2], br[3]};
    __builtin_nontemporal_store(v, (vflt4*)(out + 3u*VOX + base0));
    v = (vflt4){br[4], br[5], br[6], br[7]};
    __builtin_nontemporal_store(v, (vflt4*)(out + 3u*VOX + base1));
}

extern "C" void kernel_launch(void* const* d_in, const int* in_sizes, int n_in,
                              void* d_out, int out_size, void* d_ws, size_t ws_size,
                              hipStream_t stream) {
    const int*   labels  = (const int*)d_in[0];
    const float* id_int  = (const float*)d_in[1];
    const int*   id_dark = (const int*)d_in[2];
    const float* paren   = (const float*)d_in[3];
    float*       out     = (float*)d_out;

    const unsigned int threads_total = VOX / 8u;       // 2,097,152
    const unsigned int blocks = threads_total / 256u;  // 8,192
    synth_semantic_kernel<<<dim3(blocks), dim3(256), 0, stream>>>(
        labels, id_int, id_dark, paren, out);
}